// Round 1
// baseline (47.687 us; speedup 1.0000x reference)
//
#include <hip/hip_runtime.h>
#include <stdint.h>
#include <cmath>

#define NVARS   1024
#define NEDGES  3072
#define BATCHSZ 2048
#define HALF_B  (BATCHSZ/2)
#define CLIPT   10.0f

// JAX >= 0.5 defaults jax_threefry_partitionable=True. Flip to 0 if absmax
// shows the dropout masks are wrong (pre-0.5 JAX paired-counter scheme).
#define PARTITIONABLE 1

__host__ __device__ __forceinline__ void tf_round(uint32_t& x0, uint32_t& x1, int r) {
    x0 += x1;
    x1 = (x1 << r) | (x1 >> (32 - r));
    x1 ^= x0;
}

__host__ __device__ __forceinline__ void threefry2x32(uint32_t k0, uint32_t k1,
                                                      uint32_t x0, uint32_t x1,
                                                      uint32_t& o0, uint32_t& o1) {
    uint32_t k2 = k0 ^ k1 ^ 0x1BD11BDAu;
    x0 += k0; x1 += k1;
    tf_round(x0, x1, 13); tf_round(x0, x1, 15); tf_round(x0, x1, 26); tf_round(x0, x1, 6);
    x0 += k1; x1 += k2 + 1u;
    tf_round(x0, x1, 17); tf_round(x0, x1, 29); tf_round(x0, x1, 16); tf_round(x0, x1, 24);
    x0 += k2; x1 += k0 + 2u;
    tf_round(x0, x1, 13); tf_round(x0, x1, 15); tf_round(x0, x1, 26); tf_round(x0, x1, 6);
    x0 += k0; x1 += k1 + 3u;
    tf_round(x0, x1, 17); tf_round(x0, x1, 29); tf_round(x0, x1, 16); tf_round(x0, x1, 24);
    x0 += k1; x1 += k2 + 4u;
    tf_round(x0, x1, 13); tf_round(x0, x1, 15); tf_round(x0, x1, 26); tf_round(x0, x1, 6);
    x0 += k2; x1 += k0 + 5u;
    o0 = x0; o1 = x1;
}

// tanh(0.5*o) = 1 - 2/(1 + e^o); abs err ~1e-7, fine vs 7.8e-3 threshold.
__device__ __forceinline__ float tanh_half(float o) {
    float ex = __expf(o);
    return 1.0f - 2.0f * __builtin_amdgcn_rcpf(ex + 1.0f);
}

// Per-edge precompute: sibling edges (same var, different check), their
// odd_weights entries, the llr skip weight, and keep_prob = sigmoid(logit).
__global__ void setup_kernel(const float* __restrict__ oddw,
                             const float* __restrict__ llrw,
                             const float* __restrict__ logits,
                             const int* __restrict__ evar,
                             const int* __restrict__ echk,
                             float4* __restrict__ wkp,
                             int4* __restrict__ sidx) {
    int e = blockIdx.x * blockDim.x + threadIdx.x;
    if (e >= NEDGES) return;
    int v = evar[e];
    int r = e % 3;
    int base = e - r;
    int o1 = base + ((r + 1) % 3);
    int o2 = base + ((r + 2) % 3);
    int ce = echk[e];
    float w1 = (echk[o1] != ce) ? oddw[(size_t)o1 * NEDGES + e] : 0.0f;
    float w2 = (echk[o2] != ce) ? oddw[(size_t)o2 * NEDGES + e] : 0.0f;
    float vw = llrw[(size_t)v * NEDGES + e];
    float kp = (float)(1.0 / (1.0 + exp(-(double)logits[e])));
    wkp[e]  = make_float4(w1, w2, vw, kp);
    sidx[e] = make_int4(o1, o2, v, 0);
}

__global__ __launch_bounds__(256) void
odd_layer_kernel(const float* __restrict__ x, const float* __restrict__ llr,
                 const float4* __restrict__ wkp, const int4* __restrict__ sidx,
                 float* __restrict__ out,
                 uint32_t k0a, uint32_t k1a, uint32_t k0b, uint32_t k1b,
                 uint32_t k0c, uint32_t k1c) {
    int e = blockIdx.x * 256 + threadIdx.x;   // 0..3071
    int b = blockIdx.y;                       // 0..1023 (handles rows b and b+1024)

    float4 w = wkp[e];
    int4  s = sidx[e];

    const float* xr1 = x + (size_t)b * NEDGES;
    const float* xr2 = xr1 + (size_t)HALF_B * NEDGES;
    float xa1 = xr1[s.x] * w.x + xr1[s.y] * w.y;   // x_after_mask, row b
    float xa2 = xr2[s.x] * w.x + xr2[s.y] * w.y;   // x_after_mask, row b+1024
    float t1  = llr[(size_t)b * NVARS + s.z] * w.z;
    float t2  = llr[(size_t)(b + HALF_B) * NVARS + s.z] * w.z;

    uint32_t i1 = (uint32_t)b * NEDGES + (uint32_t)e;
    uint32_t i2 = i1 + (uint32_t)HALF_B * NEDGES;

    const uint32_t K0[3] = {k0a, k0b, k0c};
    const uint32_t K1[3] = {k1a, k1b, k1c};

    float acc1 = 0.0f, acc2 = 0.0f;
#pragma unroll
    for (int j = 0; j < 3; j++) {
        uint32_t bits1, bits2;
#if PARTITIONABLE
        uint32_t a0, a1, b0, b1;
        threefry2x32(K0[j], K1[j], 0u, i1, a0, a1);
        threefry2x32(K0[j], K1[j], 0u, i2, b0, b1);
        bits1 = a0 ^ a1;
        bits2 = b0 ^ b1;
#else
        // original scheme: counts iota(n) split in halves; element i (< n/2)
        // pairs with i + n/2; here i2 == i1 + n/2 exactly.
        threefry2x32(K0[j], K1[j], i1, i2, bits1, bits2);
#endif
        float u1 = __uint_as_float((bits1 >> 9) | 0x3f800000u) - 1.0f;
        float u2 = __uint_as_float((bits2 >> 9) | 0x3f800000u) - 1.0f;
        float odd1 = xa1 + ((u1 < w.w) ? t1 : 0.0f);
        float odd2 = xa2 + ((u2 < w.w) ? t2 : 0.0f);
        odd1 = fminf(fmaxf(odd1, -CLIPT), CLIPT);
        odd2 = fminf(fmaxf(odd2, -CLIPT), CLIPT);
        acc1 += tanh_half(odd1);
        acc2 += tanh_half(odd2);
    }
    out[i1] = acc1 * (1.0f / 3.0f);
    out[i2] = acc2 * (1.0f / 3.0f);
}

extern "C" void kernel_launch(void* const* d_in, const int* in_sizes, int n_in,
                              void* d_out, int out_size, void* d_ws, size_t ws_size,
                              hipStream_t stream) {
    const float* x      = (const float*)d_in[0];
    const float* llr    = (const float*)d_in[1];
    const float* oddw   = (const float*)d_in[2];
    const float* llrw   = (const float*)d_in[3];
    const float* logits = (const float*)d_in[4];
    const int*   evar   = (const int*)d_in[5];
    const int*   echk   = (const int*)d_in[6];
    float* out = (float*)d_out;

    float4* wkp  = (float4*)d_ws;
    int4*   sidx = (int4*)((char*)d_ws + (size_t)NEDGES * sizeof(float4));

    // Host-side reproduction of jax.random.split(jax.random.key(42), 3).
    // Base key data = (0, 42).
    uint32_t k0[3], k1[3];
#if PARTITIONABLE
    for (uint32_t j = 0; j < 3; j++) {
        threefry2x32(0u, 42u, 0u, j, k0[j], k1[j]);
    }
#else
    {
        uint32_t o0[3], o1[3];
        for (uint32_t t = 0; t < 3; t++) threefry2x32(0u, 42u, t, t + 3u, o0[t], o1[t]);
        uint32_t outb[6] = {o0[0], o0[1], o0[2], o1[0], o1[1], o1[2]};
        k0[0] = outb[0]; k1[0] = outb[1];
        k0[1] = outb[2]; k1[1] = outb[3];
        k0[2] = outb[4]; k1[2] = outb[5];
    }
#endif

    setup_kernel<<<(NEDGES + 255) / 256, 256, 0, stream>>>(oddw, llrw, logits, evar, echk, wkp, sidx);

    dim3 grid(NEDGES / 256, HALF_B);
    odd_layer_kernel<<<grid, 256, 0, stream>>>(x, llr, wkp, sidx, out,
                                               k0[0], k1[0], k0[1], k1[1], k0[2], k1[2]);
}

// Round 2
// 47.315 us; speedup vs baseline: 1.0079x; 1.0079x over previous
//
#include <hip/hip_runtime.h>
#include <stdint.h>
#include <cmath>

#define NVARS   1024
#define NEDGES  3072
#define BATCHSZ 2048
#define RPT     4
#define ROWSTR  (BATCHSZ/RPT)   /* 512 */
#define CLIPT   10.0f

// JAX >= 0.5 threefry_partitionable scheme (verified bit-exact in round 1).
__host__ __device__ __forceinline__ void tf_round(uint32_t& x0, uint32_t& x1, int r) {
    x0 += x1;
    x1 = (x1 << r) | (x1 >> (32 - r));   // -> v_alignbit_b32
    x1 ^= x0;
}

__host__ __device__ __forceinline__ void threefry2x32(uint32_t k0, uint32_t k1,
                                                      uint32_t x0, uint32_t x1,
                                                      uint32_t& o0, uint32_t& o1) {
    uint32_t k2 = k0 ^ k1 ^ 0x1BD11BDAu;
    x0 += k0; x1 += k1;
    tf_round(x0, x1, 13); tf_round(x0, x1, 15); tf_round(x0, x1, 26); tf_round(x0, x1, 6);
    x0 += k1; x1 += k2 + 1u;
    tf_round(x0, x1, 17); tf_round(x0, x1, 29); tf_round(x0, x1, 16); tf_round(x0, x1, 24);
    x0 += k2; x1 += k0 + 2u;
    tf_round(x0, x1, 13); tf_round(x0, x1, 15); tf_round(x0, x1, 26); tf_round(x0, x1, 6);
    x0 += k0; x1 += k1 + 3u;
    tf_round(x0, x1, 17); tf_round(x0, x1, 29); tf_round(x0, x1, 16); tf_round(x0, x1, 24);
    x0 += k1; x1 += k2 + 4u;
    tf_round(x0, x1, 13); tf_round(x0, x1, 15); tf_round(x0, x1, 26); tf_round(x0, x1, 6);
    x0 += k2; x1 += k0 + 5u;
    o0 = x0; o1 = x1;
}

// tanh(0.5*o) = 1 - 2/(1 + e^o)
__device__ __forceinline__ float tanh_half(float o) {
    float ex = __expf(o);
    return 1.0f - 2.0f * __builtin_amdgcn_rcpf(ex + 1.0f);
}

// Per-edge precompute. w.w holds the integer dropout threshold T9 (bit-cast):
//   u < kp  <=>  (bits>>9) < ceil(kp*2^23)  <=>  bits < T9 = ceil(kp*2^23)<<9
// (exact: u = (bits>>9)*2^-23 exactly; low 9 bits of T9 are zero).
__global__ void setup_kernel(const float* __restrict__ oddw,
                             const float* __restrict__ llrw,
                             const float* __restrict__ logits,
                             const int* __restrict__ evar,
                             const int* __restrict__ echk,
                             float4* __restrict__ wkp,
                             int4* __restrict__ sidx) {
    int e = blockIdx.x * blockDim.x + threadIdx.x;
    if (e >= NEDGES) return;
    int v = evar[e];
    int r = e % 3;
    int base = e - r;
    int o1 = base + ((r + 1) % 3);
    int o2 = base + ((r + 2) % 3);
    int ce = echk[e];
    float w1 = (echk[o1] != ce) ? oddw[(size_t)o1 * NEDGES + e] : 0.0f;
    float w2 = (echk[o2] != ce) ? oddw[(size_t)o2 * NEDGES + e] : 0.0f;
    float vw = llrw[(size_t)v * NEDGES + e];
    // identical kp float as round 1 (keeps mask decisions bit-identical)
    float kpf = (float)(1.0 / (1.0 + exp(-(double)logits[e])));
    double Td = ceil((double)kpf * 8388608.0);
    uint32_t T9;
    if (Td >= 8388608.0) T9 = 0xFFFFFFFFu;
    else                 T9 = ((uint32_t)Td) << 9;
    wkp[e]  = make_float4(w1, w2, vw, __uint_as_float(T9));
    sidx[e] = make_int4(o1, o2, v, 0);
}

__global__ __launch_bounds__(256) void
odd_layer_kernel(const float* __restrict__ x, const float* __restrict__ llr,
                 const float4* __restrict__ wkp, const int4* __restrict__ sidx,
                 float* __restrict__ out,
                 uint32_t k0a, uint32_t k1a, uint32_t k0b, uint32_t k1b,
                 uint32_t k0c, uint32_t k1c) {
    int e = blockIdx.x * 256 + threadIdx.x;   // 0..3071
    int b0 = blockIdx.y;                      // 0..511; rows b0 + 512*r

    float4 w = wkp[e];
    int4   s = sidx[e];
    uint32_t T9 = __float_as_uint(w.w);

    float    xa[RPT], tv[RPT];
    uint32_t idx[RPT];
    int      cnt[RPT];
#pragma unroll
    for (int r = 0; r < RPT; r++) {
        int b = b0 + r * ROWSTR;
        const float* xr = x + (size_t)b * NEDGES;
        float xs1 = xr[s.x];
        float xs2 = xr[s.y];
        float lv  = llr[b * NVARS + s.z];
        xa[r]  = xs1 * w.x + xs2 * w.y;
        tv[r]  = lv * w.z;
        idx[r] = (uint32_t)b * NEDGES + (uint32_t)e;
        cnt[r] = 0;
    }

    const uint32_t K0[3] = {k0a, k0b, k0c};
    const uint32_t K1[3] = {k1a, k1b, k1c};

    // 12 independent threefry chains: per member j, per row r.
#pragma unroll
    for (int j = 0; j < 3; j++) {
#pragma unroll
        for (int r = 0; r < RPT; r++) {
            uint32_t o0, o1;
            threefry2x32(K0[j], K1[j], 0u, idx[r], o0, o1);
            cnt[r] += ((o0 ^ o1) < T9) ? 1 : 0;
        }
    }

#pragma unroll
    for (int r = 0; r < RPT; r++) {
        float a0 = fminf(fmaxf(xa[r],          -CLIPT), CLIPT);
        float a1 = fminf(fmaxf(xa[r] + tv[r],  -CLIPT), CLIPT);
        float t0 = tanh_half(a0);
        float t1 = tanh_half(a1);
        // mean of 3 members = t0 + cnt*(t1-t0)/3
        out[idx[r]] = fmaf((float)cnt[r], (t1 - t0) * (1.0f / 3.0f), t0);
    }
}

extern "C" void kernel_launch(void* const* d_in, const int* in_sizes, int n_in,
                              void* d_out, int out_size, void* d_ws, size_t ws_size,
                              hipStream_t stream) {
    const float* x      = (const float*)d_in[0];
    const float* llr    = (const float*)d_in[1];
    const float* oddw   = (const float*)d_in[2];
    const float* llrw   = (const float*)d_in[3];
    const float* logits = (const float*)d_in[4];
    const int*   evar   = (const int*)d_in[5];
    const int*   echk   = (const int*)d_in[6];
    float* out = (float*)d_out;

    float4* wkp  = (float4*)d_ws;
    int4*   sidx = (int4*)((char*)d_ws + (size_t)NEDGES * sizeof(float4));

    // jax.random.split(jax.random.key(42), 3), partitionable scheme.
    uint32_t k0[3], k1[3];
    for (uint32_t j = 0; j < 3; j++) {
        threefry2x32(0u, 42u, 0u, j, k0[j], k1[j]);
    }

    setup_kernel<<<(NEDGES + 255) / 256, 256, 0, stream>>>(oddw, llrw, logits, evar, echk, wkp, sidx);

    dim3 grid(NEDGES / 256, ROWSTR);
    odd_layer_kernel<<<grid, 256, 0, stream>>>(x, llr, wkp, sidx, out,
                                               k0[0], k1[0], k0[1], k1[1], k0[2], k1[2]);
}

// Round 3
// 46.983 us; speedup vs baseline: 1.0150x; 1.0071x over previous
//
#include <hip/hip_runtime.h>
#include <stdint.h>
#include <cmath>

#define NVARS   1024
#define NEDGES  3072
#define BATCHSZ 2048
#define RPT     4
#define ROWSTR  (BATCHSZ/RPT)   /* 512 */
#define CLIPT   10.0f

// Single-instruction rotate: v_alignbit_b32 computes (s0:s1)>>s2, so
// rotl(x,r) == alignbit(x,x,32-r). Host fallback for the key computation.
__host__ __device__ __forceinline__ uint32_t rotl32(uint32_t x, int r) {
#if defined(__HIP_DEVICE_COMPILE__)
    return __builtin_amdgcn_alignbit(x, x, (uint32_t)(32 - r));
#else
    return (x << r) | (x >> (32 - r));
#endif
}

// Reference (host) threefry for key derivation.
__host__ __forceinline__ void threefry2x32_host(uint32_t k0, uint32_t k1,
                                                uint32_t x0, uint32_t x1,
                                                uint32_t& o0, uint32_t& o1) {
    uint32_t k2 = k0 ^ k1 ^ 0x1BD11BDAu;
    const int rots[20] = {13,15,26,6, 17,29,16,24, 13,15,26,6, 17,29,16,24, 13,15,26,6};
    x0 += k0; x1 += k1;
    int rc = 0;
    const uint32_t ka[5] = {k1, k2, k0, k1, k2};
    const uint32_t kb[5] = {k2, k0, k1, k2, k0};
    for (int g = 0; g < 5; g++) {
        for (int i = 0; i < 4; i++) {
            x0 += x1; x1 = rotl32(x1, rots[rc++]); x1 ^= x0;
        }
        x0 += ka[g]; x1 += kb[g] + (uint32_t)(g + 1);
    }
    o0 = x0; o1 = x1;
}

// Device: two independent threefry chains interleaved (explicit ILP=2),
// returning o0^o1 (the only thing the dropout mask needs).
__device__ __forceinline__ void threefry_dual_xor(uint32_t k0, uint32_t k1,
                                                  uint32_t ia, uint32_t ib,
                                                  uint32_t& oa, uint32_t& ob) {
    uint32_t k2 = k0 ^ k1 ^ 0x1BD11BDAu;
    uint32_t a0 = k0, a1 = ia + k1;
    uint32_t b0 = k0, b1 = ib + k1;
#define R2(r) do { \
        a0 += a1;            b0 += b1; \
        a1 = rotl32(a1, r);  b1 = rotl32(b1, r); \
        a1 ^= a0;            b1 ^= b0; } while (0)
    R2(13); R2(15); R2(26); R2(6);
    a0 += k1; b0 += k1; a1 += k2 + 1u; b1 += k2 + 1u;
    R2(17); R2(29); R2(16); R2(24);
    a0 += k2; b0 += k2; a1 += k0 + 2u; b1 += k0 + 2u;
    R2(13); R2(15); R2(26); R2(6);
    a0 += k0; b0 += k0; a1 += k1 + 3u; b1 += k1 + 3u;
    R2(17); R2(29); R2(16); R2(24);
    a0 += k1; b0 += k1; a1 += k2 + 4u; b1 += k2 + 4u;
    R2(13); R2(15); R2(26); R2(6);
    a0 += k2; b0 += k2; a1 += k0 + 5u; b1 += k0 + 5u;
#undef R2
    oa = a0 ^ a1;
    ob = b0 ^ b1;
}

// tanh(0.5*o) = 1 - 2/(1 + e^o)
__device__ __forceinline__ float tanh_half(float o) {
    float ex = __expf(o);
    return 1.0f - 2.0f * __builtin_amdgcn_rcpf(ex + 1.0f);
}

// Per-edge precompute. w.w holds the integer dropout threshold T9 (bit-cast):
//   u < kp  <=>  bits < T9 = ceil(kp*2^23)<<9   (exact)
__global__ void setup_kernel(const float* __restrict__ oddw,
                             const float* __restrict__ llrw,
                             const float* __restrict__ logits,
                             const int* __restrict__ evar,
                             const int* __restrict__ echk,
                             float4* __restrict__ wkp,
                             int4* __restrict__ sidx) {
    int e = blockIdx.x * blockDim.x + threadIdx.x;
    if (e >= NEDGES) return;
    int v = evar[e];
    int r = e % 3;
    int base = e - r;
    int o1 = base + ((r + 1) % 3);
    int o2 = base + ((r + 2) % 3);
    int ce = echk[e];
    float w1 = (echk[o1] != ce) ? oddw[(size_t)o1 * NEDGES + e] : 0.0f;
    float w2 = (echk[o2] != ce) ? oddw[(size_t)o2 * NEDGES + e] : 0.0f;
    float vw = llrw[(size_t)v * NEDGES + e];
    float kpf = (float)(1.0 / (1.0 + exp(-(double)logits[e])));
    double Td = ceil((double)kpf * 8388608.0);
    uint32_t T9;
    if (Td >= 8388608.0) T9 = 0xFFFFFFFFu;
    else                 T9 = ((uint32_t)Td) << 9;
    wkp[e]  = make_float4(w1, w2, vw, __uint_as_float(T9));
    sidx[e] = make_int4(o1, o2, v, 0);
}

__global__ __launch_bounds__(256) void
odd_layer_kernel(const float* __restrict__ x, const float* __restrict__ llr,
                 const float4* __restrict__ wkp, const int4* __restrict__ sidx,
                 float* __restrict__ out,
                 uint32_t k0a, uint32_t k1a, uint32_t k0b, uint32_t k1b,
                 uint32_t k0c, uint32_t k1c) {
    int e = blockIdx.x * 256 + threadIdx.x;   // 0..3071
    int b0 = blockIdx.y;                      // 0..511; rows b0 + 512*r

    float4 w = wkp[e];
    int4   s = sidx[e];
    uint32_t T9 = __float_as_uint(w.w);

    float    xa[RPT], tv[RPT];
    uint32_t idx[RPT];
    int      cnt[RPT];
#pragma unroll
    for (int r = 0; r < RPT; r++) {
        int b = b0 + r * ROWSTR;
        const float* xr = x + (size_t)b * NEDGES;
        float xs1 = xr[s.x];
        float xs2 = xr[s.y];
        float lv  = llr[b * NVARS + s.z];
        xa[r]  = xs1 * w.x + xs2 * w.y;
        tv[r]  = lv * w.z;
        idx[r] = (uint32_t)b * NEDGES + (uint32_t)e;
        cnt[r] = 0;
    }

    const uint32_t K0[3] = {k0a, k0b, k0c};
    const uint32_t K1[3] = {k1a, k1b, k1c};

    // 12 threefry chains: per member j, rows processed 2-at-a-time with
    // explicit instruction-level interleaving.
#pragma unroll
    for (int j = 0; j < 3; j++) {
        uint32_t m0, m1, m2, m3;
        threefry_dual_xor(K0[j], K1[j], idx[0], idx[1], m0, m1);
        threefry_dual_xor(K0[j], K1[j], idx[2], idx[3], m2, m3);
        cnt[0] += (m0 < T9) ? 1 : 0;
        cnt[1] += (m1 < T9) ? 1 : 0;
        cnt[2] += (m2 < T9) ? 1 : 0;
        cnt[3] += (m3 < T9) ? 1 : 0;
    }

#pragma unroll
    for (int r = 0; r < RPT; r++) {
        float a0 = fminf(fmaxf(xa[r],          -CLIPT), CLIPT);
        float a1 = fminf(fmaxf(xa[r] + tv[r],  -CLIPT), CLIPT);
        float t0 = tanh_half(a0);
        float t1 = tanh_half(a1);
        out[idx[r]] = fmaf((float)cnt[r], (t1 - t0) * (1.0f / 3.0f), t0);
    }
}

extern "C" void kernel_launch(void* const* d_in, const int* in_sizes, int n_in,
                              void* d_out, int out_size, void* d_ws, size_t ws_size,
                              hipStream_t stream) {
    const float* x      = (const float*)d_in[0];
    const float* llr    = (const float*)d_in[1];
    const float* oddw   = (const float*)d_in[2];
    const float* llrw   = (const float*)d_in[3];
    const float* logits = (const float*)d_in[4];
    const int*   evar   = (const int*)d_in[5];
    const int*   echk   = (const int*)d_in[6];
    float* out = (float*)d_out;

    float4* wkp  = (float4*)d_ws;
    int4*   sidx = (int4*)((char*)d_ws + (size_t)NEDGES * sizeof(float4));

    // jax.random.split(jax.random.key(42), 3), partitionable scheme.
    uint32_t k0[3], k1[3];
    for (uint32_t j = 0; j < 3; j++) {
        threefry2x32_host(0u, 42u, 0u, j, k0[j], k1[j]);
    }

    setup_kernel<<<(NEDGES + 255) / 256, 256, 0, stream>>>(oddw, llrw, logits, evar, echk, wkp, sidx);

    dim3 grid(NEDGES / 256, ROWSTR);
    odd_layer_kernel<<<grid, 256, 0, stream>>>(x, llr, wkp, sidx, out,
                                               k0[0], k1[0], k0[1], k1[1], k0[2], k1[2]);
}

// Round 4
// 44.731 us; speedup vs baseline: 1.0661x; 1.0503x over previous
//
#include <hip/hip_runtime.h>
#include <stdint.h>
#include <cmath>

#define NVARS   1024
#define NEDGES  3072
#define BATCHSZ 2048
#define RPT     4
#define ROWSTR  (BATCHSZ/RPT)   /* 512 */

// Single-instruction rotate on device.
__host__ __device__ __forceinline__ uint32_t rotl32(uint32_t x, int r) {
#if defined(__HIP_DEVICE_COMPILE__)
    return __builtin_amdgcn_alignbit(x, x, (uint32_t)(32 - r));
#else
    return (x << r) | (x >> (32 - r));
#endif
}

// Host threefry for key derivation (jax.random.split of key(42)).
__host__ __forceinline__ void threefry2x32_host(uint32_t k0, uint32_t k1,
                                                uint32_t x0, uint32_t x1,
                                                uint32_t& o0, uint32_t& o1) {
    uint32_t k2 = k0 ^ k1 ^ 0x1BD11BDAu;
    const int rots[20] = {13,15,26,6, 17,29,16,24, 13,15,26,6, 17,29,16,24, 13,15,26,6};
    x0 += k0; x1 += k1;
    int rc = 0;
    const uint32_t ka[5] = {k1, k2, k0, k1, k2};
    const uint32_t kb[5] = {k2, k0, k1, k2, k0};
    for (int g = 0; g < 5; g++) {
        for (int i = 0; i < 4; i++) {
            x0 += x1; x1 = rotl32(x1, rots[rc++]); x1 ^= x0;
        }
        x0 += ka[g]; x1 += kb[g] + (uint32_t)(g + 1);
    }
    o0 = x0; o1 = x1;
}

// Four independent threefry chains, instruction-interleaved (explicit ILP=4).
// Returns o0^o1 per chain (all the dropout mask needs).
__device__ __forceinline__ void threefry_quad_xor(
        uint32_t k0, uint32_t k1,
        uint32_t i0, uint32_t i1, uint32_t i2, uint32_t i3,
        uint32_t& m0, uint32_t& m1, uint32_t& m2, uint32_t& m3) {
    uint32_t k2 = k0 ^ k1 ^ 0x1BD11BDAu;
    uint32_t a0 = k0, a1 = i0 + k1;
    uint32_t b0 = k0, b1 = i1 + k1;
    uint32_t c0 = k0, c1 = i2 + k1;
    uint32_t d0 = k0, d1 = i3 + k1;
#define R4(r) \
    a0 += a1; b0 += b1; c0 += c1; d0 += d1; \
    a1 = rotl32(a1, r); b1 = rotl32(b1, r); c1 = rotl32(c1, r); d1 = rotl32(d1, r); \
    a1 ^= a0; b1 ^= b0; c1 ^= c0; d1 ^= d0;
#define INJ4(ka, kb) \
    a0 += (ka); b0 += (ka); c0 += (ka); d0 += (ka); \
    a1 += (kb); b1 += (kb); c1 += (kb); d1 += (kb);
    R4(13) R4(15) R4(26) R4(6)  INJ4(k1, k2 + 1u)
    R4(17) R4(29) R4(16) R4(24) INJ4(k2, k0 + 2u)
    R4(13) R4(15) R4(26) R4(6)  INJ4(k0, k1 + 3u)
    R4(17) R4(29) R4(16) R4(24) INJ4(k1, k2 + 4u)
    R4(13) R4(15) R4(26) R4(6)  INJ4(k2, k0 + 5u)
#undef R4
#undef INJ4
    m0 = a0 ^ a1; m1 = b0 ^ b1; m2 = c0 ^ c1; m3 = d0 ^ d1;
}

// tanh(0.5*o) = 1 - 2/(1 + e^o). Saturates correctly for any |o| (inf-safe),
// so the reference's clip(+-10) is numerically dead (error <= 9.1e-5 even
// when |o|>10, far under the 7.8e-3 threshold; on this data |o| << 10).
__device__ __forceinline__ float tanh_half(float o) {
    float ex = __expf(o);
    return 1.0f - 2.0f * __builtin_amdgcn_rcpf(ex + 1.0f);
}

// Per-edge precompute. w.w holds the integer dropout threshold T9 (bit-cast):
//   u < kp  <=>  bits < T9 = ceil(kp*2^23)<<9   (exact)
__global__ void setup_kernel(const float* __restrict__ oddw,
                             const float* __restrict__ llrw,
                             const float* __restrict__ logits,
                             const int* __restrict__ evar,
                             const int* __restrict__ echk,
                             float4* __restrict__ wkp,
                             int4* __restrict__ sidx) {
    int e = blockIdx.x * blockDim.x + threadIdx.x;
    if (e >= NEDGES) return;
    int v = evar[e];
    int r = e % 3;
    int base = e - r;
    int o1 = base + ((r + 1) % 3);
    int o2 = base + ((r + 2) % 3);
    int ce = echk[e];
    float w1 = (echk[o1] != ce) ? oddw[(size_t)o1 * NEDGES + e] : 0.0f;
    float w2 = (echk[o2] != ce) ? oddw[(size_t)o2 * NEDGES + e] : 0.0f;
    float vw = llrw[(size_t)v * NEDGES + e];
    float kpf = (float)(1.0 / (1.0 + exp(-(double)logits[e])));
    double Td = ceil((double)kpf * 8388608.0);
    uint32_t T9;
    if (Td >= 8388608.0) T9 = 0xFFFFFFFFu;
    else                 T9 = ((uint32_t)Td) << 9;
    wkp[e]  = make_float4(w1, w2, vw, __uint_as_float(T9));
    sidx[e] = make_int4(o1, o2, v, 0);
}

#define ISTEP ((uint32_t)ROWSTR * NEDGES)        /* 1572864 elements  */
#define XSTEP (ISTEP * 4u)                       /* 6291456 bytes     */
#define LSTEP ((uint32_t)ROWSTR * NVARS * 4u)    /* 2097152 bytes     */

__global__ __launch_bounds__(256, 8) void
odd_layer_kernel(const float* __restrict__ x, const float* __restrict__ llr,
                 const float4* __restrict__ wkp, const int4* __restrict__ sidx,
                 float* __restrict__ out,
                 uint32_t k0a, uint32_t k1a, uint32_t k0b, uint32_t k1b,
                 uint32_t k0c, uint32_t k1c) {
    const int e  = blockIdx.x * 256 + threadIdx.x;   // 0..3071
    const int b0 = blockIdx.y;                       // 0..511

    // Wave-uniform byte bases (SGPR); per-access offsets are 32-bit VGPRs.
    const char* xb = (const char*)(x   + (size_t)b0 * NEDGES);
    const char* lb = (const char*)(llr + (size_t)b0 * NVARS);
    char*       ob = (char*)      (out + (size_t)b0 * NEDGES);

    float4 w = wkp[e];
    int4   s = sidx[e];
    const uint32_t T9 = __float_as_uint(w.w);

    const uint32_t i0 = (uint32_t)b0 * NEDGES + (uint32_t)e;
    const uint32_t i1 = i0 + ISTEP, i2 = i0 + 2u * ISTEP, i3 = i0 + 3u * ISTEP;

    // Member 0 threefry first: pure-VALU work that overlaps the wkp/sidx
    // load latency (T9/s only needed afterwards).
    uint32_t p0, p1, p2, p3;
    threefry_quad_xor(k0a, k1a, i0, i1, i2, i3, p0, p1, p2, p3);

    // Gathers (need s): issue now, consumed after members 1-2 (~600 insts).
    const uint32_t sx4 = (uint32_t)s.x << 2;
    const uint32_t sy4 = (uint32_t)s.y << 2;
    const uint32_t sz4 = (uint32_t)s.z << 2;
    float xv1[RPT], xv2[RPT], lvv[RPT];
#pragma unroll
    for (int r = 0; r < RPT; r++) {
        xv1[r] = *(const float*)(xb + (sx4 + r * XSTEP));
        xv2[r] = *(const float*)(xb + (sy4 + r * XSTEP));
        lvv[r] = *(const float*)(lb + (sz4 + r * LSTEP));
    }

    uint32_t q0, q1, q2, q3, r0, r1, r2, r3;
    threefry_quad_xor(k0b, k1b, i0, i1, i2, i3, q0, q1, q2, q3);
    threefry_quad_xor(k0c, k1c, i0, i1, i2, i3, r0, r1, r2, r3);

    int cnt[RPT];
    cnt[0] = ((p0 < T9) ? 1 : 0) + ((q0 < T9) ? 1 : 0) + ((r0 < T9) ? 1 : 0);
    cnt[1] = ((p1 < T9) ? 1 : 0) + ((q1 < T9) ? 1 : 0) + ((r1 < T9) ? 1 : 0);
    cnt[2] = ((p2 < T9) ? 1 : 0) + ((q2 < T9) ? 1 : 0) + ((r2 < T9) ? 1 : 0);
    cnt[3] = ((p3 < T9) ? 1 : 0) + ((q3 < T9) ? 1 : 0) + ((r3 < T9) ? 1 : 0);

    const uint32_t e4 = (uint32_t)e << 2;
#pragma unroll
    for (int r = 0; r < RPT; r++) {
        float xa = fmaf(xv2[r], w.y, xv1[r] * w.x);
        float t0 = tanh_half(xa);
        float t1 = tanh_half(fmaf(lvv[r], w.z, xa));
        float cf = (float)cnt[r];
        *(float*)(ob + (e4 + r * XSTEP)) = fmaf(cf, (t1 - t0) * (1.0f / 3.0f), t0);
    }
}

extern "C" void kernel_launch(void* const* d_in, const int* in_sizes, int n_in,
                              void* d_out, int out_size, void* d_ws, size_t ws_size,
                              hipStream_t stream) {
    const float* x      = (const float*)d_in[0];
    const float* llr    = (const float*)d_in[1];
    const float* oddw   = (const float*)d_in[2];
    const float* llrw   = (const float*)d_in[3];
    const float* logits = (const float*)d_in[4];
    const int*   evar   = (const int*)d_in[5];
    const int*   echk   = (const int*)d_in[6];
    float* out = (float*)d_out;

    float4* wkp  = (float4*)d_ws;
    int4*   sidx = (int4*)((char*)d_ws + (size_t)NEDGES * sizeof(float4));

    // jax.random.split(jax.random.key(42), 3), partitionable scheme.
    uint32_t k0[3], k1[3];
    for (uint32_t j = 0; j < 3; j++) {
        threefry2x32_host(0u, 42u, 0u, j, k0[j], k1[j]);
    }

    setup_kernel<<<(NEDGES + 255) / 256, 256, 0, stream>>>(oddw, llrw, logits, evar, echk, wkp, sidx);

    dim3 grid(NEDGES / 256, ROWSTR);
    odd_layer_kernel<<<grid, 256, 0, stream>>>(x, llr, wkp, sidx, out,
                                               k0[0], k1[0], k0[1], k1[1], k0[2], k1[2]);
}